// Round 1
// baseline (365.333 us; speedup 1.0000x reference)
//
#include <hip/hip_runtime.h>

// UnigramLM forward-backward posterior, T=2048, L=8, V=32000.
// R8: SINGLE fused kernel, zero cross-block sync.
//   Block 0:    forward scan THEN backward scan (serial, both hidden under the
//               fill wall), alpha/beta kept entirely in LDS, then plain-stores
//               the posterior values to the scatter-target addresses.
//   Blocks 1..: zero-fill of one (row, half) = 64,000 B each, SKIPPING the
//               <=8 scatter-target floats of that half (addresses derivable
//               from midx alone). Disjoint write sets => no ordering needed,
//               no atomics, no flags, dispatch-order independent.

#define NEGV -1e9f
#define LOG2E 1.4426950408889634f
constexpr int T = 2048;
constexpr int L = 8;
constexpr int V = 32000;
constexpr int NCH = 64;   // chunks per scan
constexpr int K = 32;     // steps per chunk (NCH*K == T)
constexpr int BLK = 512;
constexpr int HALF = V / 2;        // 16,000 floats per fill block
constexpr int H4 = HALF / 4;       // 4,000 float4 per fill block
constexpr int FILLB = 2 * T;       // 4096 fill blocks: (row, half)
constexpr int CPAD = K * 8 + 4;    // 260 floats/chunk (phase-1/3 pad)

__device__ __forceinline__ float hexp2(float x) { return __builtin_amdgcn_exp2f(x); }
__device__ __forceinline__ float hlog2(float x) { return __builtin_amdgcn_logf(x); }

__device__ __forceinline__ float lse8v(float t0, float t1, float t2, float t3,
                                       float t4, float t5, float t6, float t7) {
    float m = fmaxf(fmaxf(fmaxf(t0, t1), fmaxf(t2, t3)),
                    fmaxf(fmaxf(t4, t5), fmaxf(t6, t7)));
    float s = hexp2(t0 - m) + hexp2(t1 - m) + hexp2(t2 - m) + hexp2(t3 - m)
            + hexp2(t4 - m) + hexp2(t5 - m) + hexp2(t6 - m) + hexp2(t7 - m);
    return m + hlog2(s);
}

__global__ __launch_bounds__(BLK) void fused_kernel(
        const float* __restrict__ logp, const int* __restrict__ midx,
        float* __restrict__ out) {
    const int tid = threadIdx.x;
    const int bx = blockIdx.x;

    __shared__ __align__(16) float sW[NCH * CPAD];   // 66,560 B staged w (log2 dom)
    __shared__ __align__(16) float sPm[NCH * 64];    // 16,384 B chunk operators
    __shared__ float sVst[(NCH + 1) * 8];            //  2,080 B boundary states
    __shared__ float sOutA[NCH * 33];                //  8,448 B alpha emit (padded)
    __shared__ float sOutB[NCH * 33];                //  8,448 B beta  emit (padded)
    // total 101,920 B -> 1 block/CU

    if (bx > 0) {
        // ---------------- fill block: (row t, half) ----------------
        const int idx = bx - 1;
        const int t = idx >> 1;
        const int half = idx & 1;
        const int cbase = half * HALF;

        int* sM = (int*)sW;                       // reuse LDS for midx broadcast
        if (tid < 8) sM[tid] = midx[(t << 3) + tid];
        __syncthreads();

        // scatter-target columns of THIS half (to be skipped; scan block writes them)
        int tcol[8], tf4[8];
#pragma unroll
        for (int j = 0; j < 8; ++j) {
            int m = sM[j];
            bool sp = (m >= cbase) && (m < cbase + HALF);   // m<0 excluded (cbase>=0)
            tcol[j] = sp ? (m - cbase) : -1;
            tf4[j]  = sp ? (m - cbase) >> 2 : -1;
        }

        float4 z = make_float4(0.f, 0.f, 0.f, 0.f);
        float4* o4 = (float4*)(out + (size_t)t * V + cbase);
        for (int i = tid; i < H4; i += BLK) {
            bool sp = false;
#pragma unroll
            for (int j = 0; j < 8; ++j) sp |= (i == tf4[j]);
            if (!sp) {
                o4[i] = z;                         // plain 16B store (rocclr-style)
            } else {
                float* of = (float*)(o4 + i);      // rare: <=8 float4s per block
#pragma unroll
                for (int c = 0; c < 4; ++c) {
                    int col = i * 4 + c;
                    bool hit = false;
#pragma unroll
                    for (int j = 0; j < 8; ++j) hit |= (col == tcol[j]);
                    if (!hit) of[c] = 0.f;         // zero non-target lanes only
                }
            }
        }
        return;
    }

    // ---------------- block 0: fwd scan, bwd scan, scatter ----------------
    for (int pass = 0; pass < 2; ++pass) {
        // ---- staging: gathers into LDS; row r at sW[(r>>5)*CPAD + (r&31)*8 + j]
        if (pass == 0) {
            // forward: row r holds wrev[r][j] = w[r-j][j]
            for (int o = tid; o < T * L; o += BLK) {
                int r = o >> 3, j = o & 7, t = r - j;
                float v = NEGV;
                if (t >= 0) { int m = midx[(t << 3) + j]; if (m >= 0) v = logp[m] * LOG2E; }
                sW[(r >> 5) * CPAD + (r & 31) * 8 + j] = v;
            }
        } else {
            // backward: row s holds w[T-1-s][j]
            for (int o = tid; o < T * L; o += BLK) {
                int s = o >> 3, j = o & 7, t = T - 1 - s;
                int m = midx[(t << 3) + j];
                sW[(s >> 5) * CPAD + (s & 31) * 8 + j] = (m >= 0) ? logp[m] * LOG2E : NEGV;
            }
        }
        __syncthreads();

        // ---- phase 1: operator composition; thread (c, col); 8 thr/chunk
        {
            const int c = tid >> 3, col = tid & 7;
            float q[8];
#pragma unroll
            for (int i = 0; i < 8; ++i) q[i] = (i == col) ? 0.f : NEGV;
            const float* wc = &sW[c * CPAD];
            float4 c0 = *(const float4*)(wc + 0), c1 = *(const float4*)(wc + 4);
            float4 b0 = *(const float4*)(wc + 8), b1 = *(const float4*)(wc + 12);
            for (int k = 0; k < K; ++k) {
                float4 a0, a1;
                if (k + 2 < K) {
                    a0 = *(const float4*)(wc + (k + 2) * 8);
                    a1 = *(const float4*)(wc + (k + 2) * 8 + 4);
                }
                float top = lse8v(c0.x + q[0], c0.y + q[1], c0.z + q[2], c0.w + q[3],
                                  c1.x + q[4], c1.y + q[5], c1.z + q[6], c1.w + q[7]);
#pragma unroll
                for (int i = 7; i > 0; --i) q[i] = q[i - 1];
                q[0] = top;
                c0 = b0; c1 = b1; b0 = a0; b1 = a1;
            }
#pragma unroll
            for (int i = 0; i < 8; ++i) sPm[c * 64 + i * 8 + col] = q[i];
        }
        __syncthreads();

        // ---- phase 2: sequential combine across chunks (lanes 0..7)
        if (tid < 8) {
            const int r = tid;
            float v = (r == 0) ? 0.f : NEGV;
            float4 r0 = *(const float4*)&sPm[r * 8];
            float4 r1 = *(const float4*)&sPm[r * 8 + 4];
            for (int cc = 0; cc < NCH; ++cc) {
                sVst[cc * 8 + r] = v;
                float4 n0, n1;
                if (cc + 1 < NCH) {
                    n0 = *(const float4*)&sPm[(cc + 1) * 64 + r * 8];
                    n1 = *(const float4*)&sPm[(cc + 1) * 64 + r * 8 + 4];
                }
                float vb0 = __shfl(v, 0, 8), vb1 = __shfl(v, 1, 8);
                float vb2 = __shfl(v, 2, 8), vb3 = __shfl(v, 3, 8);
                float vb4 = __shfl(v, 4, 8), vb5 = __shfl(v, 5, 8);
                float vb6 = __shfl(v, 6, 8), vb7 = __shfl(v, 7, 8);
                v = lse8v(r0.x + vb0, r0.y + vb1, r0.z + vb2, r0.w + vb3,
                          r1.x + vb4, r1.y + vb5, r1.z + vb6, r1.w + vb7);
                r0 = n0; r1 = n1;
            }
            sVst[NCH * 8 + r] = v;
        }
        __syncthreads();

        // ---- phase 3: re-run each chunk from boundary state into padded emit buf
        {
            float* so = pass ? sOutB : sOutA;
            if (tid < NCH) {
                const int cc = tid;
                float ab[8];
#pragma unroll
                for (int i = 0; i < 8; ++i) ab[i] = sVst[cc * 8 + i];
                const float* wc = &sW[cc * CPAD];
                float4 c0 = *(const float4*)(wc + 0), c1 = *(const float4*)(wc + 4);
                float4 b0 = *(const float4*)(wc + 8), b1 = *(const float4*)(wc + 12);
                for (int k = 0; k < K; ++k) {
                    float4 a0, a1;
                    if (k + 2 < K) {
                        a0 = *(const float4*)(wc + (k + 2) * 8);
                        a1 = *(const float4*)(wc + (k + 2) * 8 + 4);
                    }
                    float val = lse8v(c0.x + ab[0], c0.y + ab[1], c0.z + ab[2], c0.w + ab[3],
                                      c1.x + ab[4], c1.y + ab[5], c1.z + ab[6], c1.w + ab[7]);
                    so[cc * 33 + k] = val;   // bank (cc+k)%32: 2-way, free
#pragma unroll
                    for (int i = 7; i > 0; --i) ab[i] = ab[i - 1];
                    ab[0] = val;
                    c0 = b0; c1 = b1; b0 = a0; b1 = a1;
                }
            }
        }
        __syncthreads();   // protects sW/sPm/sVst reuse in pass 1 + sOut reads below
    }

    // alpha[n] (n>=1) lives at sOutA[((n-1)>>5)*33 + ((n-1)&31)]; alpha[0]=0.
    // beta[x]  (x< T) lives at sOutB[(s>>5)*33 + (s&31)], s = T-1-x; beta[T]=0.

    // ---- stage midx into LDS (sW is free now), then scatter plain stores ----
    int* sM = (int*)sW;
    for (int o = tid; o < T * L; o += BLK) sM[o] = midx[o];
    __syncthreads();

    const float aT = sOutA[((T - 1) >> 5) * 33 + ((T - 1) & 31)];   // alpha[T]
    for (int o = tid; o < T * L; o += BLK) {
        int t = o >> 3, j = o & 7;
        int m = sM[o];
        if (m < 0) continue;
        const int rb = t << 3;
        // dedupe: only the lowest j with this m writes (sums all duplicates)
        bool lowest = true;
        for (int jj = 0; jj < j; ++jj) lowest &= (sM[rb + jj] != m);
        if (!lowest) continue;
        float a_t = (t == 0) ? 0.f : sOutA[((t - 1) >> 5) * 33 + ((t - 1) & 31)];
        float lp = logp[m] * LOG2E;
        float s = 0.f;
        for (int jj = j; jj < 8; ++jj) {
            if (sM[rb + jj] != m) continue;
            int nx = t + jj + 1; if (nx > T) nx = T;
            float b = (nx == T) ? 0.f
                                : sOutB[((T - 1 - nx) >> 5) * 33 + ((T - 1 - nx) & 31)];
            s += hexp2(a_t + lp + b - aT);
        }
        out[(size_t)t * V + m] = s;   // address skipped by the fill blocks
    }
}

extern "C" void kernel_launch(void* const* d_in, const int* in_sizes, int n_in,
                              void* d_out, int out_size, void* d_ws, size_t ws_size,
                              hipStream_t stream) {
    const float* logp = (const float*)d_in[0];   // [V]
    const int*   midx = (const int*)d_in[1];     // [T, L]
    float* out = (float*)d_out;                  // [T, V]

    fused_kernel<<<dim3(1 + FILLB), BLK, 0, stream>>>(logp, midx, out);
}

// Round 2
// 296.368 us; speedup vs baseline: 1.2327x; 1.2327x over previous
//
#include <hip/hip_runtime.h>

// UnigramLM forward-backward posterior, T=2048, L=8, V=32000.
// R9: split by LDS need.
//   Kernel A (scan): 2 blocks, 102KB LDS each — block 0 forward scan, block 1
//     backward scan (R7-proven code), alpha/beta (log2 domain) -> workspace.
//   Kernel B (fill+scatter): 2048 blocks x 256 thr, ZERO LDS -> 8 blocks/CU,
//     ALL blocks resident in one round. Each block owns one output row:
//     float4 zero-stream, __syncthreads (drains own stores), then thread 0
//     plain-stores the row's <=8 dedupe-summed posterior values.
//     Block-private writes => no cross-block ordering, no atomics.

#define NEGV -1e9f
#define LOG2E 1.4426950408889634f
constexpr int T = 2048;
constexpr int L = 8;
constexpr int V = 32000;
constexpr int NCH = 64;   // chunks per scan
constexpr int K = 32;     // steps per chunk (NCH*K == T)
constexpr int BLK = 512;
constexpr int CPAD = K * 8 + 4;    // 260 floats/chunk (phase-1/3 pad)
constexpr int R4 = V / 4;          // 8000 float4 per row

__device__ __forceinline__ float hexp2(float x) { return __builtin_amdgcn_exp2f(x); }
__device__ __forceinline__ float hlog2(float x) { return __builtin_amdgcn_logf(x); }

__device__ __forceinline__ float lse8v(float t0, float t1, float t2, float t3,
                                       float t4, float t5, float t6, float t7) {
    float m = fmaxf(fmaxf(fmaxf(t0, t1), fmaxf(t2, t3)),
                    fmaxf(fmaxf(t4, t5), fmaxf(t6, t7)));
    float s = hexp2(t0 - m) + hexp2(t1 - m) + hexp2(t2 - m) + hexp2(t3 - m)
            + hexp2(t4 - m) + hexp2(t5 - m) + hexp2(t6 - m) + hexp2(t7 - m);
    return m + hlog2(s);
}

__global__ __launch_bounds__(BLK) void scan_kernel(
        const float* __restrict__ logp, const int* __restrict__ midx,
        float* __restrict__ alpha, float* __restrict__ beta) {
    const int tid = threadIdx.x;
    const int bx = blockIdx.x;

    __shared__ __align__(16) float sW[NCH * CPAD];   // 66,560 B staged w (log2 dom)
    __shared__ __align__(16) float sPm[NCH * 64];    // 16,384 B chunk operators
    __shared__ float sVst[(NCH + 1) * 8];            //  2,080 B boundary states
    __shared__ float sOut[NCH * 33];                 //  8,448 B padded emit buffer

    // ---- staging: gathers into LDS; row r at sW[(r>>5)*CPAD + (r&31)*8 + j]
    if (bx == 0) {
        // forward: row r holds wrev[r][j] = w[r-j][j]
        for (int o = tid; o < T * L; o += BLK) {
            int r = o >> 3, j = o & 7, t = r - j;
            float v = NEGV;
            if (t >= 0) { int m = midx[(t << 3) + j]; if (m >= 0) v = logp[m] * LOG2E; }
            sW[(r >> 5) * CPAD + (r & 31) * 8 + j] = v;
        }
    } else {
        // backward: row s holds w[T-1-s][j]
        for (int o = tid; o < T * L; o += BLK) {
            int s = o >> 3, j = o & 7, t = T - 1 - s;
            int m = midx[(t << 3) + j];
            sW[(s >> 5) * CPAD + (s & 31) * 8 + j] = (m >= 0) ? logp[m] * LOG2E : NEGV;
        }
    }
    __syncthreads();

    // ---- phase 1: operator composition; thread (c, col); 8 thr/chunk
    {
        const int c = tid >> 3, col = tid & 7;
        float q[8];
#pragma unroll
        for (int i = 0; i < 8; ++i) q[i] = (i == col) ? 0.f : NEGV;
        const float* wc = &sW[c * CPAD];
        float4 c0 = *(const float4*)(wc + 0), c1 = *(const float4*)(wc + 4);
        float4 b0 = *(const float4*)(wc + 8), b1 = *(const float4*)(wc + 12);
        for (int k = 0; k < K; ++k) {
            float4 a0, a1;
            if (k + 2 < K) {
                a0 = *(const float4*)(wc + (k + 2) * 8);
                a1 = *(const float4*)(wc + (k + 2) * 8 + 4);
            }
            float top = lse8v(c0.x + q[0], c0.y + q[1], c0.z + q[2], c0.w + q[3],
                              c1.x + q[4], c1.y + q[5], c1.z + q[6], c1.w + q[7]);
#pragma unroll
            for (int i = 7; i > 0; --i) q[i] = q[i - 1];
            q[0] = top;
            c0 = b0; c1 = b1; b0 = a0; b1 = a1;
        }
#pragma unroll
        for (int i = 0; i < 8; ++i) sPm[c * 64 + i * 8 + col] = q[i];
    }
    __syncthreads();

    // ---- phase 2: sequential combine across chunks (lanes 0..7, LDS prefetch)
    if (tid < 8) {
        const int r = tid;
        float v = (r == 0) ? 0.f : NEGV;
        float4 r0 = *(const float4*)&sPm[r * 8];
        float4 r1 = *(const float4*)&sPm[r * 8 + 4];
        for (int cc = 0; cc < NCH; ++cc) {
            sVst[cc * 8 + r] = v;
            float4 n0, n1;
            if (cc + 1 < NCH) {
                n0 = *(const float4*)&sPm[(cc + 1) * 64 + r * 8];
                n1 = *(const float4*)&sPm[(cc + 1) * 64 + r * 8 + 4];
            }
            float vb0 = __shfl(v, 0, 8), vb1 = __shfl(v, 1, 8);
            float vb2 = __shfl(v, 2, 8), vb3 = __shfl(v, 3, 8);
            float vb4 = __shfl(v, 4, 8), vb5 = __shfl(v, 5, 8);
            float vb6 = __shfl(v, 6, 8), vb7 = __shfl(v, 7, 8);
            v = lse8v(r0.x + vb0, r0.y + vb1, r0.z + vb2, r0.w + vb3,
                      r1.x + vb4, r1.y + vb5, r1.z + vb6, r1.w + vb7);
            r0 = n0; r1 = n1;
        }
        sVst[NCH * 8 + r] = v;
    }
    __syncthreads();

    // ---- phase 3: re-run each chunk from boundary state into padded emit buf
    if (tid < NCH) {
        const int cc = tid;
        float ab[8];
#pragma unroll
        for (int i = 0; i < 8; ++i) ab[i] = sVst[cc * 8 + i];
        const float* wc = &sW[cc * CPAD];
        float4 c0 = *(const float4*)(wc + 0), c1 = *(const float4*)(wc + 4);
        float4 b0 = *(const float4*)(wc + 8), b1 = *(const float4*)(wc + 12);
        for (int k = 0; k < K; ++k) {
            float4 a0, a1;
            if (k + 2 < K) {
                a0 = *(const float4*)(wc + (k + 2) * 8);
                a1 = *(const float4*)(wc + (k + 2) * 8 + 4);
            }
            float val = lse8v(c0.x + ab[0], c0.y + ab[1], c0.z + ab[2], c0.w + ab[3],
                              c1.x + ab[4], c1.y + ab[5], c1.z + ab[6], c1.w + ab[7]);
            sOut[cc * 33 + k] = val;   // bank (cc+k)%32: 2-way, free
#pragma unroll
            for (int i = 7; i > 0; --i) ab[i] = ab[i - 1];
            ab[0] = val;
            c0 = b0; c1 = b1; b0 = a0; b1 = a1;
        }
    }
    __syncthreads();

    // ---- coalesced dump of alpha / beta to global (log2 domain)
    if (bx == 0) {
        for (int o = tid; o < T; o += BLK)
            alpha[o + 1] = sOut[(o >> 5) * 33 + (o & 31)];
        if (tid == 0) alpha[0] = 0.f;
    } else {
        for (int o = tid; o < T; o += BLK) {
            int s = T - 1 - o;   // phase3 step s emitted beta[T-1-s]
            beta[o] = sOut[(s >> 5) * 33 + (s & 31)];
        }
        if (tid == 0) beta[T] = 0.f;
    }
}

__global__ __launch_bounds__(256) void fill_scatter_kernel(
        const float* __restrict__ logp, const int* __restrict__ midx,
        float* __restrict__ out, const float* __restrict__ alpha,
        const float* __restrict__ beta) {
    const int t = blockIdx.x;          // one output row per block
    const int tid = threadIdx.x;

    // ---- scatter inputs, issued early (hidden under the fill stream) ----
    int m[8];
    float lp[8], bt[8], a_t = 0.f, aT = 0.f;
    if (tid == 0) {
        int4 r0 = ((const int4*)(midx + (t << 3)))[0];
        int4 r1 = ((const int4*)(midx + (t << 3)))[1];
        m[0] = r0.x; m[1] = r0.y; m[2] = r0.z; m[3] = r0.w;
        m[4] = r1.x; m[5] = r1.y; m[6] = r1.z; m[7] = r1.w;
        a_t = alpha[t];
        aT = alpha[T];
#pragma unroll
        for (int j = 0; j < 8; ++j) {
            int mm = m[j] < 0 ? 0 : m[j];
            lp[j] = logp[mm];
            int nx = t + j + 1; if (nx > T) nx = T;
            bt[j] = beta[nx];
        }
    }

    // ---- pure float4 zero-stream over this row (128,000 B) ----
    float4 z = make_float4(0.f, 0.f, 0.f, 0.f);
    float4* o4 = (float4*)(out + (size_t)t * V);
    for (int i = tid; i < R4; i += 256) o4[i] = z;

    __syncthreads();   // drains this block's stores (vmcnt(0) before s_barrier)

    // ---- thread 0: dedupe-summed posterior stores (block-private addresses) ----
    if (tid == 0) {
#pragma unroll
        for (int j = 0; j < 8; ++j) {
            if (m[j] < 0) continue;
            bool lowest = true;
#pragma unroll
            for (int jj = 0; jj < 8; ++jj)
                if (jj < j) lowest &= (m[jj] != m[j]);
            if (!lowest) continue;
            float s = 0.f;
#pragma unroll
            for (int jj = 0; jj < 8; ++jj)
                if (jj >= j && m[jj] == m[j])
                    s += hexp2(a_t + lp[jj] * LOG2E + bt[jj] - aT);
            out[(size_t)t * V + m[j]] = s;
        }
    }
}

extern "C" void kernel_launch(void* const* d_in, const int* in_sizes, int n_in,
                              void* d_out, int out_size, void* d_ws, size_t ws_size,
                              hipStream_t stream) {
    const float* logp = (const float*)d_in[0];   // [V]
    const int*   midx = (const int*)d_in[1];     // [T, L]
    float* out = (float*)d_out;                  // [T, V]

    float* ws    = (float*)d_ws;
    float* alpha = ws;                 // 2049 -> pad 2064 (log2 domain)
    float* beta  = alpha + 2064;       // 2049 (log2 domain)

    scan_kernel<<<dim3(2), BLK, 0, stream>>>(logp, midx, alpha, beta);
    fill_scatter_kernel<<<dim3(T), 256, 0, stream>>>(logp, midx, out, alpha, beta);
}